// Round 16
// baseline (34.262 us; speedup 1.0000x reference)
//
#include <hip/hip_runtime.h>

typedef __attribute__((ext_vector_type(8))) __bf16 bf16x8;
typedef __attribute__((ext_vector_type(4))) __bf16 bf16x4;
typedef __attribute__((ext_vector_type(8))) unsigned short u16x8;
typedef __attribute__((ext_vector_type(4))) float f32x4;

#define LDST 68   // LDS row stride in bf16 (136 B): 2-bank row skew, b128 reads conflict-free

#define T_HI 0.97467943f   // sqrt(0.95)
#define T_LO 0.70710678f   // sqrt(0.5)

// Barrier draining only LDS ops (lgkmcnt) — global stores stay in flight.
__device__ __forceinline__ void lds_barrier() {
    asm volatile("s_waitcnt lgkmcnt(0)" ::: "memory");
    __builtin_amdgcn_s_barrier();
    __builtin_amdgcn_sched_barrier(0);
}
// Full drain — once, before the diagonal overwrite.
__device__ __forceinline__ void full_barrier() {
    asm volatile("s_waitcnt vmcnt(0) lgkmcnt(0)" ::: "memory");
    __builtin_amdgcn_s_barrier();
    __builtin_amdgcn_sched_barrier(0);
}

// ---- prep: fp32 X -> compact bf16 copy in d_ws (4 MB -> 2 MB, ~1 us) ----
// Panel re-reads in the main kernel then cost half the bytes and the per-batch
// panel (256 KB) is trivially L2-resident per XCD.
__global__ __launch_bounds__(256) void prep_bf16_kernel(
    const float* __restrict__ X, unsigned short* __restrict__ Xh)
{
    const int idx = blockIdx.x * 256 + threadIdx.x;   // one float4 each
    float4 v = reinterpret_cast<const float4*>(X)[idx];
    bf16x4 h = {(__bf16)v.x, (__bf16)v.y, (__bf16)v.z, (__bf16)v.w};
    *reinterpret_cast<bf16x4*>(&Xh[idx * 4]) = h;
}

// Block = 64-row strip x all 2048 cols of one batch. 1024 threads = 16 waves;
// wave w owns panel rows [16w,16w+16) of each 256-wide column tile.
// Panels stream from the bf16 copy: 16-B u16x8 loads, no cvt in the loop.
// Grid: 256 blocks (1/CU); batch = id & 7 (one batch per XCD, L2-resident panel).
__global__ __launch_bounds__(1024, 4) void lap_strip64_kernel(
    const unsigned short* __restrict__ Xh, float* __restrict__ out, int N)
{
    const int flat   = blockIdx.x;
    const int b      = flat & 7;
    const int strip0 = (flat >> 3) * 64;
    const int tid  = threadIdx.x;     // 0..1023
    const int lane = tid & 63;
    const int w    = tid >> 6;        // wave 0..15
    const int t    = lane & 15;
    const int g    = lane >> 4;

    __shared__ __align__(16) unsigned short As[2][256 * LDST];  // 256-row col-panel, dbuf (68 KB)
    __shared__ __align__(16) unsigned short Bs[64 * LDST];      // strip (loop-invariant)
    __shared__ float deg_part[16][64];

    const unsigned short* Xb = Xh + (size_t)b * N * 64;
    float* outb = out + (size_t)b * N * N;

    // ---- stage strip rows: 64 x 64 bf16 (512 x 16-B chunks; tid<512) ----
    if (tid < 512) {
        const int r = tid >> 3, q = tid & 7;
        u16x8 v = *reinterpret_cast<const u16x8*>(&Xb[((size_t)strip0 + r) * 64 + q * 8]);
        *reinterpret_cast<u16x8*>(&Bs[r * LDST + q * 8]) = v;
    }

    // ---- stage col-panel 0 into As[0] (256 rows = 2048 chunks = 2/thread) ----
    u16x8 pre[2];
    {
#pragma unroll
        for (int it = 0; it < 2; ++it) {
            const int idx = tid + it * 1024;
            const int r = idx >> 3, q = idx & 7;
            pre[it] = *reinterpret_cast<const u16x8*>(&Xb[(size_t)r * 64 + q * 8]);
        }
#pragma unroll
        for (int it = 0; it < 2; ++it) {
            const int idx = tid + it * 1024;
            const int r = idx >> 3, q = idx & 7;
            *reinterpret_cast<u16x8*>(&As[0][r * LDST + q * 8]) = pre[it];
        }
    }
    lds_barrier();

    // strip fragments: loop-invariant (4 fj covering 64 strip rows)
    bf16x8 bfrag[2][4];   // [ks][fj]
#pragma unroll
    for (int ks = 0; ks < 2; ++ks)
#pragma unroll
        for (int fj = 0; fj < 4; ++fj)
            bfrag[ks][fj] = *reinterpret_cast<const bf16x8*>(
                &Bs[(16 * fj + t) * LDST + ks * 32 + g * 8]);

    float rs[4] = {0.f, 0.f, 0.f, 0.f};
    int cur = 0;
    const int nct = N >> 8;            // 8 column tiles of 256
    const int diag_ct = strip0 >> 8;   // 64-row strip never straddles a 256 boundary

    for (int ct = 0; ct < nct; ++ct) {
        // prefetch next 256-row panel (loads issued BEFORE this iter's stores)
        if (ct + 1 < nct) {
            const unsigned short* src = Xb + (size_t)(ct + 1) * 256 * 64;
#pragma unroll
            for (int it = 0; it < 2; ++it) {
                const int idx = tid + it * 1024;
                const int r = idx >> 3, q = idx & 7;
                pre[it] = *reinterpret_cast<const u16x8*>(&src[(size_t)r * 64 + q * 8]);
            }
        }

        // ---- compute: wave w -> panel rows [16w,16w+16) x strip 64 rows ----
        f32x4 acc[4] = {};   // [fj]
#pragma unroll
        for (int ks = 0; ks < 2; ++ks) {
            const int koff = ks * 32 + g * 8;
            bf16x8 a = *reinterpret_cast<const bf16x8*>(
                &As[cur][(16 * w + t) * LDST + koff]);
#pragma unroll
            for (int fj = 0; fj < 4; ++fj)
                acc[fj] = __builtin_amdgcn_mfma_f32_16x16x32_bf16(
                    a, bfrag[ks][fj], acc[fj], 0, 0, 0);
        }

        // ---- epilogue: |d| thresholds; transposed store -> contiguous f32x4 ----
        const bool has_diag = (ct == diag_ct);
        const int ocol0 = ct * 256 + 16 * w + 4 * g;      // output col base (panel side)
#pragma unroll
        for (int fj = 0; fj < 4; ++fj) {
            const int orow = strip0 + 16 * fj + t;        // output row (strip side)
            float wv[4];
#pragma unroll
            for (int r = 0; r < 4; ++r) {
                const float d = acc[fj][r];
                float wt = (fabsf(d) >= T_HI) ? 1.0f
                         : ((fabsf(d) >= T_LO) ? 0.5f : 0.0f);
                if (has_diag && (ocol0 + r == orow)) wt = 0.0f;
                rs[fj] += wt;
                wv[r] = -wt;
            }
            f32x4 st = {wv[0], wv[1], wv[2], wv[3]};
            *reinterpret_cast<f32x4*>(&outb[(size_t)orow * N + ocol0]) = st;
        }

        // ---- write next panel into the other buffer ----
        if (ct + 1 < nct) {
#pragma unroll
            for (int it = 0; it < 2; ++it) {
                const int idx = tid + it * 1024;
                const int r = idx >> 3, q = idx & 7;
                *reinterpret_cast<u16x8*>(&As[cur ^ 1][r * LDST + q * 8]) = pre[it];
            }
        }
        lds_barrier();
        cur ^= 1;
    }

    // ---- degree: reduce over g via shfl, across 16 waves via LDS ----
#pragma unroll
    for (int fj = 0; fj < 4; ++fj) {
        rs[fj] += __shfl_xor(rs[fj], 16, 64);
        rs[fj] += __shfl_xor(rs[fj], 32, 64);
    }
    if (g == 0) {
#pragma unroll
        for (int fj = 0; fj < 4; ++fj) deg_part[w][16 * fj + t] = rs[fj];
    }
    full_barrier();   // all tile stores must land before the diagonal overwrite
    if (tid < 64) {
        float d = 0.f;
#pragma unroll
        for (int ww = 0; ww < 16; ++ww) d += deg_part[ww][tid];
        const int rr = strip0 + tid;
        outb[(size_t)rr * N + rr] = d;   // diagonal = degree
    }
}

extern "C" void kernel_launch(void* const* d_in, const int* in_sizes, int n_in,
                              void* d_out, int out_size, void* d_ws, size_t ws_size,
                              hipStream_t stream) {
    const float* X = (const float*)d_in[0];
    float* out = (float*)d_out;
    unsigned short* Xh = (unsigned short*)d_ws;    // 2 MB bf16 copy

    const int B = 8;
    const int D = 64;
    const int N = in_sizes[0] / (B * D);   // 2048

    const int nf4 = (B * N * D) / 4;       // 262144 float4s
    prep_bf16_kernel<<<nf4 / 256, dim3(256), 0, stream>>>(X, Xh);

    dim3 grid((N / 64) * B);               // 256 blocks, batch = id & 7
    lap_strip64_kernel<<<grid, dim3(1024), 0, stream>>>(Xh, out, N);
}

// Round 17
// 30.482 us; speedup vs baseline: 1.1240x; 1.1240x over previous
//
#include <hip/hip_runtime.h>

typedef __attribute__((ext_vector_type(8))) __bf16 bf16x8;
typedef __attribute__((ext_vector_type(4))) __bf16 bf16x4;
typedef __attribute__((ext_vector_type(4))) float f32x4;

#define LDST 68   // LDS row stride in bf16 (136 B): 2-bank row skew, b128 reads ~2-way max (free)

#define T_HI 0.97467943f   // sqrt(0.95)
#define T_LO 0.70710678f   // sqrt(0.5)

// Block = 64-row strip x all 2048 cols of one batch. 1024 threads = 16 waves.
// NO in-loop barriers: wave w only ever consumes panel rows [16w,16w+16), so each
// wave stages its own 4 KB slice into a PRIVATE LDS region (double-buffered) and
// relies on its own lgkmcnt ordering. Waves drift out of phase -> store issue
// spreads across the whole iteration instead of phase-locked bursts.
// Grid: 256 blocks (1/CU, 16 waves/CU); batch = id & 7 (one batch per XCD).
__global__ __launch_bounds__(1024, 4) void lap_nobar_kernel(
    const float* __restrict__ X, float* __restrict__ out, int N)
{
    const int flat   = blockIdx.x;
    const int b      = flat & 7;
    const int strip0 = (flat >> 3) * 64;
    const int tid  = threadIdx.x;     // 0..1023
    const int lane = tid & 63;
    const int w    = tid >> 6;        // wave 0..15
    const int t    = lane & 15;
    const int g    = lane >> 4;

    __shared__ __align__(16) unsigned short Bs[64 * LDST];          // strip (read-only after barrier)
    __shared__ __align__(16) unsigned short Aw[16][2][16 * LDST];   // per-wave private panel dbuf (70 KB)
    __shared__ float deg_part[16][64];

    const float* Xb   = X   + (size_t)b * N * 64;
    float*       outb = out + (size_t)b * N * N;

    // ---- stage strip rows: 64 x 64 fp32 -> bf16 (1024 float4, one per thread) ----
    {
        const float4* src = reinterpret_cast<const float4*>(Xb + (size_t)strip0 * 64);
        int r = tid >> 4, q = tid & 15;
        float4 v = src[tid];
        bf16x4 h = {(__bf16)v.x, (__bf16)v.y, (__bf16)v.z, (__bf16)v.w};
        *reinterpret_cast<bf16x4*>(&Bs[r * LDST + q * 4]) = h;
    }
    __syncthreads();   // the ONLY block-wide barrier before the end

    // strip fragments: loop-invariant (4 fj covering 64 strip rows)
    bf16x8 bfrag[2][4];   // [ks][fj]
#pragma unroll
    for (int ks = 0; ks < 2; ++ks)
#pragma unroll
        for (int fj = 0; fj < 4; ++fj)
            bfrag[ks][fj] = *reinterpret_cast<const bf16x8*>(
                &Bs[(16 * fj + t) * LDST + ks * 32 + g * 8]);

    // ---- per-wave private staging helpers ----
    float4 pre[4];   // wave slice: 16 rows x 64 floats = 256 float4 = 4 per lane

#define LOADP(ct_)                                                              \
    {                                                                           \
        const float4* src_ = reinterpret_cast<const float4*>(                   \
            Xb + (size_t)(256 * (ct_) + 16 * w) * 64);                          \
        _Pragma("unroll")                                                       \
        for (int j = 0; j < 4; ++j) pre[j] = src_[j * 64 + lane];               \
    }

#define STAGEP(buf_)                                                            \
    {                                                                           \
        _Pragma("unroll")                                                       \
        for (int j = 0; j < 4; ++j) {                                           \
            int idx_ = j * 64 + lane;                                           \
            int r_ = idx_ >> 4, q_ = idx_ & 15;                                 \
            float4 v_ = pre[j];                                                 \
            bf16x4 h_ = {(__bf16)v_.x, (__bf16)v_.y, (__bf16)v_.z, (__bf16)v_.w}; \
            *reinterpret_cast<bf16x4*>(&Aw[w][buf_][r_ * LDST + q_ * 4]) = h_;  \
        }                                                                       \
    }

    float rs[4] = {0.f, 0.f, 0.f, 0.f};
    const int nct = N >> 8;            // 8 column tiles of 256
    const int diag_ct = strip0 >> 8;

    LOADP(0);
    STAGEP(0);
    int cur = 0;

    for (int ct = 0; ct < nct; ++ct) {
        // issue next slice's loads first (stores stay behind them in vmcnt order)
        if (ct + 1 < nct) LOADP(ct + 1);

        // ---- compute: wave w -> panel rows [16w,16w+16) x strip 64 rows ----
        // (compiler inserts the lgkmcnt wait on this wave's own ds_write)
        f32x4 acc[4] = {};   // [fj]
#pragma unroll
        for (int ks = 0; ks < 2; ++ks) {
            bf16x8 a = *reinterpret_cast<const bf16x8*>(
                &Aw[w][cur][t * LDST + ks * 32 + g * 8]);
#pragma unroll
            for (int fj = 0; fj < 4; ++fj)
                acc[fj] = __builtin_amdgcn_mfma_f32_16x16x32_bf16(
                    a, bfrag[ks][fj], acc[fj], 0, 0, 0);
        }

        // ---- epilogue: |d| thresholds; transposed store -> contiguous f32x4 ----
        const bool has_diag = (ct == diag_ct);
        const int ocol0 = ct * 256 + 16 * w + 4 * g;
#pragma unroll
        for (int fj = 0; fj < 4; ++fj) {
            const int orow = strip0 + 16 * fj + t;
            float wv[4];
#pragma unroll
            for (int r = 0; r < 4; ++r) {
                const float d = acc[fj][r];
                float wt = (fabsf(d) >= T_HI) ? 1.0f
                         : ((fabsf(d) >= T_LO) ? 0.5f : 0.0f);
                if (has_diag && (ocol0 + r == orow)) wt = 0.0f;
                rs[fj] += wt;
                wv[r] = -wt;
            }
            f32x4 st = {wv[0], wv[1], wv[2], wv[3]};
            *reinterpret_cast<f32x4*>(&outb[(size_t)orow * N + ocol0]) = st;
        }

        // stage next slice into the other private buffer (waits only the loads)
        if (ct + 1 < nct) STAGEP(cur ^ 1);
        cur ^= 1;
    }
#undef LOADP
#undef STAGEP

    // ---- degree: reduce over g via shfl, across 16 waves via LDS ----
#pragma unroll
    for (int fj = 0; fj < 4; ++fj) {
        rs[fj] += __shfl_xor(rs[fj], 16, 64);
        rs[fj] += __shfl_xor(rs[fj], 32, 64);
    }
    if (g == 0) {
#pragma unroll
        for (int fj = 0; fj < 4; ++fj) deg_part[w][16 * fj + t] = rs[fj];
    }
    __syncthreads();   // full drain (vmcnt+lgkmcnt): all tile stores land first
    if (tid < 64) {
        float d = 0.f;
#pragma unroll
        for (int ww = 0; ww < 16; ++ww) d += deg_part[ww][tid];
        const int rr = strip0 + tid;
        outb[(size_t)rr * N + rr] = d;   // diagonal = degree
    }
}

extern "C" void kernel_launch(void* const* d_in, const int* in_sizes, int n_in,
                              void* d_out, int out_size, void* d_ws, size_t ws_size,
                              hipStream_t stream) {
    const float* X = (const float*)d_in[0];
    float* out = (float*)d_out;

    const int B = 8;
    const int D = 64;
    const int N = in_sizes[0] / (B * D);   // 2048

    dim3 grid((N / 64) * B);               // 256 blocks, batch = id & 7
    lap_nobar_kernel<<<grid, dim3(1024), 0, stream>>>(X, out, N);
}

// Round 18
// 29.722 us; speedup vs baseline: 1.1527x; 1.0256x over previous
//
#include <hip/hip_runtime.h>

typedef __attribute__((ext_vector_type(8))) __bf16 bf16x8;
typedef __attribute__((ext_vector_type(4))) __bf16 bf16x4;
typedef __attribute__((ext_vector_type(4))) float f32x4;

#define LDST 68   // LDS row stride in bf16 (136 B): 2-bank row skew, b128 reads conflict-free

#define T_HI 0.97467943f   // sqrt(0.95)
#define T_LO 0.70710678f   // sqrt(0.5)

// Barrier draining only LDS ops (lgkmcnt) — global stores stay in flight.
__device__ __forceinline__ void lds_barrier() {
    asm volatile("s_waitcnt lgkmcnt(0)" ::: "memory");
    __builtin_amdgcn_s_barrier();
    __builtin_amdgcn_sched_barrier(0);
}
// Full drain — once, before the diagonal overwrite.
__device__ __forceinline__ void full_barrier() {
    asm volatile("s_waitcnt vmcnt(0) lgkmcnt(0)" ::: "memory");
    __builtin_amdgcn_s_barrier();
    __builtin_amdgcn_sched_barrier(0);
}

// Block = 64-row strip x all 2048 cols of one batch. 1024 threads = 16 waves;
// wave w owns panel rows [16w,16w+16) of each 256-wide column tile.
// Output stores are NON-TEMPORAL: they bypass L2 allocation, so the 512-KB
// batch input stays XCD-L2-resident across all 32 re-reading blocks (the one
// lever — read traffic — that has moved the plateau).
// Grid: 256 blocks (1/CU); batch = id & 7 (one batch per XCD).
__global__ __launch_bounds__(1024, 4) void lap_strip64_kernel(
    const float* __restrict__ X, float* __restrict__ out, int N)
{
    const int flat   = blockIdx.x;
    const int b      = flat & 7;
    const int strip0 = (flat >> 3) * 64;
    const int tid  = threadIdx.x;     // 0..1023
    const int lane = tid & 63;
    const int w    = tid >> 6;        // wave 0..15
    const int t    = lane & 15;
    const int g    = lane >> 4;

    __shared__ __align__(16) unsigned short As[2][256 * LDST];  // 256-row col-panel, dbuf (68 KB)
    __shared__ __align__(16) unsigned short Bs[64 * LDST];      // strip (loop-invariant)
    __shared__ float deg_part[16][64];

    const float* Xb   = X   + (size_t)b * N * 64;
    float*       outb = out + (size_t)b * N * N;

    // ---- stage strip rows: 64 x 64 fp32 -> bf16 (1024 float4, one per thread) ----
    {
        const float4* src = reinterpret_cast<const float4*>(Xb + (size_t)strip0 * 64);
        int r = tid >> 4, q = tid & 15;
        float4 v = src[tid];
        bf16x4 h = {(__bf16)v.x, (__bf16)v.y, (__bf16)v.z, (__bf16)v.w};
        *reinterpret_cast<bf16x4*>(&Bs[r * LDST + q * 4]) = h;
    }

    // ---- stage col-panel 0 into As[0] (256 rows = 4096 float4 = 4 per thread) ----
    float4 pre[4];
    {
        const float4* src = reinterpret_cast<const float4*>(Xb);
#pragma unroll
        for (int it = 0; it < 4; ++it) pre[it] = src[tid + it * 1024];
#pragma unroll
        for (int it = 0; it < 4; ++it) {
            int idx = tid + it * 1024;
            int r = idx >> 4, q = idx & 15;
            float4 v = pre[it];
            bf16x4 h = {(__bf16)v.x, (__bf16)v.y, (__bf16)v.z, (__bf16)v.w};
            *reinterpret_cast<bf16x4*>(&As[0][r * LDST + q * 4]) = h;
        }
    }
    lds_barrier();

    // strip fragments: loop-invariant (4 fj covering 64 strip rows)
    bf16x8 bfrag[2][4];   // [ks][fj]
#pragma unroll
    for (int ks = 0; ks < 2; ++ks)
#pragma unroll
        for (int fj = 0; fj < 4; ++fj)
            bfrag[ks][fj] = *reinterpret_cast<const bf16x8*>(
                &Bs[(16 * fj + t) * LDST + ks * 32 + g * 8]);

    float rs[4] = {0.f, 0.f, 0.f, 0.f};
    int cur = 0;
    const int nct = N >> 8;            // 8 column tiles of 256
    const int diag_ct = strip0 >> 8;   // 64-row strip never straddles a 256 boundary

    for (int ct = 0; ct < nct; ++ct) {
        // prefetch next 256-row panel into regs (loads issued BEFORE this iter's stores)
        if (ct + 1 < nct) {
            const float4* src = reinterpret_cast<const float4*>(Xb + (size_t)(ct + 1) * 256 * 64);
#pragma unroll
            for (int it = 0; it < 4; ++it) pre[it] = src[tid + it * 1024];
        }

        // ---- compute: wave w -> panel rows [16w,16w+16) x strip 64 rows ----
        f32x4 acc[4] = {};   // [fj]
#pragma unroll
        for (int ks = 0; ks < 2; ++ks) {
            const int koff = ks * 32 + g * 8;
            bf16x8 a = *reinterpret_cast<const bf16x8*>(
                &As[cur][(16 * w + t) * LDST + koff]);
#pragma unroll
            for (int fj = 0; fj < 4; ++fj)
                acc[fj] = __builtin_amdgcn_mfma_f32_16x16x32_bf16(
                    a, bfrag[ks][fj], acc[fj], 0, 0, 0);
        }

        // ---- epilogue: |d| thresholds; NT store (no L2 allocate) ----
        const bool has_diag = (ct == diag_ct);
        const int ocol0 = ct * 256 + 16 * w + 4 * g;      // output col base (panel side)
#pragma unroll
        for (int fj = 0; fj < 4; ++fj) {
            const int orow = strip0 + 16 * fj + t;        // output row (strip side)
            float wv[4];
#pragma unroll
            for (int r = 0; r < 4; ++r) {
                const float d = acc[fj][r];
                float wt = (fabsf(d) >= T_HI) ? 1.0f
                         : ((fabsf(d) >= T_LO) ? 0.5f : 0.0f);
                if (has_diag && (ocol0 + r == orow)) wt = 0.0f;
                rs[fj] += wt;
                wv[r] = -wt;
            }
            f32x4 st = {wv[0], wv[1], wv[2], wv[3]};
            f32x4* dst = reinterpret_cast<f32x4*>(&outb[(size_t)orow * N + ocol0]);
            if (has_diag) *dst = st;                        // diag line: plain store
            else __builtin_nontemporal_store(st, dst);      // stream, keep input in L2
        }

        // ---- write next panel into the other buffer ----
        if (ct + 1 < nct) {
#pragma unroll
            for (int it = 0; it < 4; ++it) {
                int idx = tid + it * 1024;
                int r = idx >> 4, q = idx & 15;
                float4 v = pre[it];
                bf16x4 h = {(__bf16)v.x, (__bf16)v.y, (__bf16)v.z, (__bf16)v.w};
                *reinterpret_cast<bf16x4*>(&As[cur ^ 1][r * LDST + q * 4]) = h;
            }
        }
        lds_barrier();
        cur ^= 1;
    }

    // ---- degree: reduce over g via shfl, across 16 waves via LDS ----
#pragma unroll
    for (int fj = 0; fj < 4; ++fj) {
        rs[fj] += __shfl_xor(rs[fj], 16, 64);
        rs[fj] += __shfl_xor(rs[fj], 32, 64);
    }
    if (g == 0) {
#pragma unroll
        for (int fj = 0; fj < 4; ++fj) deg_part[w][16 * fj + t] = rs[fj];
    }
    full_barrier();   // all tile stores must land before the diagonal overwrite
    if (tid < 64) {
        float d = 0.f;
#pragma unroll
        for (int ww = 0; ww < 16; ++ww) d += deg_part[ww][tid];
        const int rr = strip0 + tid;
        outb[(size_t)rr * N + rr] = d;   // diagonal = degree
    }
}

extern "C" void kernel_launch(void* const* d_in, const int* in_sizes, int n_in,
                              void* d_out, int out_size, void* d_ws, size_t ws_size,
                              hipStream_t stream) {
    const float* X = (const float*)d_in[0];
    float* out = (float*)d_out;

    const int B = 8;
    const int D = 64;
    const int N = in_sizes[0] / (B * D);   // 2048

    dim3 grid((N / 64) * B);               // 256 blocks, batch = id & 7
    lap_strip64_kernel<<<grid, dim3(1024), 0, stream>>>(X, out, N);
}